// Round 1
// baseline (5880.534 us; speedup 1.0000x reference)
//
#include <hip/hip_runtime.h>
#include <stdint.h>

typedef short bf16x8 __attribute__((ext_vector_type(8)));
typedef float f32x4 __attribute__((ext_vector_type(4)));
typedef float f32x2 __attribute__((ext_vector_type(2)));
typedef uint32_t u32x4 __attribute__((ext_vector_type(4)));
typedef uint32_t u32x2 __attribute__((ext_vector_type(2)));
typedef unsigned short u16;
typedef long long i64;

#define ITERS 50
#define BETA_F 5.0f

// ws layout (float offsets)
#define WS_SUPSUM 0       // 1024: per-class support sums [16][64]
#define WS_COUNTS 1024    // 16
#define WS_CENT   1040    // 1024: centroids [16][64]
#define WS_CSQ    2064    // 16: |centroid|^2 (fp32, used by final)
#define WS_ACC    2080    // 8 replicas x (1024 num + 16 den)
#define WS_CORR   10400   // 1: correct-count
#define WS_Q8_OFF 10432   // fp8(e4m3) query cache starts here (byte 41728), NQ*64 bytes

__device__ __forceinline__ u16 f2bf(float x) {
  union { float f; uint32_t u; } v; v.f = x;
  uint32_t r = (v.u + 0x7FFFu + ((v.u >> 16) & 1u)) >> 16;
  return (u16)r;
}
__device__ __forceinline__ float bf2f(u16 b) {
  union { float f; uint32_t u; } v; v.u = ((uint32_t)b) << 16;
  return v.f;
}
__device__ __forceinline__ float u2f(uint32_t u) {
  union { float f; uint32_t u; } v; v.u = u;
  return v.f;
}
__device__ __forceinline__ uint32_t fkey(float f) {
  union { float f; uint32_t u; } v; v.f = f;
  return (v.u & 0x80000000u) ? ~v.u : (v.u | 0x80000000u);
}
// v_cvt_pk_bf16_f32: dst = {lo16=bf16(a), hi16=bf16(b)} (RNE, matches f2bf)
__device__ __forceinline__ uint32_t cvt_pk_bf16(float a, float b) {
  uint32_t r;
  asm("v_cvt_pk_bf16_f32 %0, %1, %2" : "=v"(r) : "v"(a), "v"(b));
  return r;
}
// pack 4 floats -> 4 e4m3 bytes (RNE)
__device__ __forceinline__ uint32_t pk8(float a, float b, float c, float d) {
  int r = __builtin_amdgcn_cvt_pk_fp8_f32(a, b, 0, false);
  r = __builtin_amdgcn_cvt_pk_fp8_f32(c, d, r, true);
  return (uint32_t)r;
}
__device__ __forceinline__ i64 pack64(uint32_t lo, uint32_t hi) {
  return (i64)(((uint64_t)hi << 32) | (uint64_t)lo);
}
// quantize 4 floats -> fp8 hi + fp8 lo (residual); accumulate |hi+lo|^2 into sq
__device__ __forceinline__ void quant_hilo4(float v0, float v1, float v2, float v3,
                                            uint32_t& hi, uint32_t& lo, float& sq) {
  uint32_t h = pk8(v0, v1, v2, v3);
  float h0 = __builtin_amdgcn_cvt_f32_fp8((int)h, 0);
  float h1 = __builtin_amdgcn_cvt_f32_fp8((int)h, 1);
  float h2 = __builtin_amdgcn_cvt_f32_fp8((int)h, 2);
  float h3 = __builtin_amdgcn_cvt_f32_fp8((int)h, 3);
  uint32_t l = pk8(v0 - h0, v1 - h1, v2 - h2, v3 - h3);
  float c0 = h0 + __builtin_amdgcn_cvt_f32_fp8((int)l, 0);
  float c1 = h1 + __builtin_amdgcn_cvt_f32_fp8((int)l, 1);
  float c2 = h2 + __builtin_amdgcn_cvt_f32_fp8((int)l, 2);
  float c3 = h3 + __builtin_amdgcn_cvt_f32_fp8((int)l, 3);
  sq += c0 * c0 + c1 * c1 + c2 * c2 + c3 * c3;
  hi = h; lo = l;
}

// ---- DPP cross-lane (VALU pipe, not LDS) ----
template <int CTRL>
__device__ __forceinline__ float dppf(float x) {
  int i = __builtin_bit_cast(int, x);
  int r = __builtin_amdgcn_update_dpp(i, i, CTRL, 0xF, 0xF, false);
  return __builtin_bit_cast(float, r);
}
template <int CTRL>
__device__ __forceinline__ uint32_t dppu(uint32_t x) {
  int r = __builtin_amdgcn_update_dpp((int)x, (int)x, CTRL, 0xF, 0xF, false);
  return (uint32_t)r;
}
__device__ __forceinline__ float rmax16(float x) {
  x = fmaxf(x, dppf<0xB1>(x));
  x = fmaxf(x, dppf<0x4E>(x));
  x = fmaxf(x, dppf<0x141>(x));
  x = fmaxf(x, dppf<0x140>(x));
  return x;
}
__device__ __forceinline__ float rsum16(float x) {
  x += dppf<0xB1>(x);
  x += dppf<0x4E>(x);
  x += dppf<0x141>(x);
  x += dppf<0x140>(x);
  return x;
}
__device__ __forceinline__ uint32_t rumax16(uint32_t x) {
  uint32_t t;
  t = dppu<0xB1>(x);  x = (t > x) ? t : x;
  t = dppu<0x4E>(x);  x = (t > x) ? t : x;
  t = dppu<0x141>(x); x = (t > x) ? t : x;
  t = dppu<0x140>(x); x = (t > x) ? t : x;
  return x;
}

// ---------- init: support sums, counts, initial centroids, zero accumulators ----------
__global__ __launch_bounds__(1024) void init_kernel(const float* __restrict__ sup,
                                                    const int* __restrict__ slab,
                                                    int NS, float* __restrict__ ws) {
  const int tid = threadIdx.x;
  const int c = tid >> 6, j = tid & 63;
  float s = 0.f; int cnt = 0;
  for (int i = 0; i < NS; ++i) {
    int lbl = slab[i];
    float v = sup[i * 64 + j];
    if (lbl == c) { s += v; cnt++; }
  }
  ws[WS_SUPSUM + tid] = s;
  if (j == 0) ws[WS_COUNTS + c] = (float)cnt;
  ws[WS_CENT + tid] = s / (float)cnt;
  for (int i = tid; i < 8 * 1040; i += 1024) ws[WS_ACC + i] = 0.f;
  if (tid == 0) ws[WS_CORR] = 0.f;
  __syncthreads();
  if (j == 0) {
    float sq = 0.f;
    for (int k = 0; k < 64; ++k) { float v = ws[WS_CENT + c * 64 + k]; sq += v * v; }
    ws[WS_CSQ + c] = sq;
  }
}

// ---------- fp32 -> fp8(e4m3) query cache (128 MiB: fully Infinity-Cache resident) ----------
__global__ __launch_bounds__(256) void convert_kernel(const float* __restrict__ qf,
                                                      u32x4* __restrict__ q8, int n16) {
  const int start = blockIdx.x * 256 + threadIdx.x;
  const int stride = gridDim.x * 256;
  const f32x4* in = (const f32x4*)qf;
  for (int k = start; k < n16; k += stride) {
    f32x4 v0 = in[4 * k + 0], v1 = in[4 * k + 1], v2 = in[4 * k + 2], v3 = in[4 * k + 3];
    u32x4 o;
    o[0] = pk8(v0[0], v0[1], v0[2], v0[3]);
    o[1] = pk8(v1[0], v1[1], v1[2], v1[3]);
    o[2] = pk8(v2[0], v2[1], v2[2], v2[3]);
    o[3] = pk8(v3[0], v3[1], v3[2], v3[3]);
    q8[k] = o;
  }
}

// ---------- one soft-assignment pass: fp8 scores -> softmax -> W^T@Q accumulate ----------
template <bool SRC_F8>
__global__ __launch_bounds__(256, 4) void pass_kernel(const float* __restrict__ qf,
                                                      const uint8_t* __restrict__ q8,
                                                      int NQ, float* __restrict__ ws) {
  // qt_w[wave][dim][word-col]: word = 2 bf16 = (query 2t, query 2t+1) of one dim,
  // word-col swizzled with ^(g<<2) to break bank conflicts (undone at read).
  __shared__ __attribute__((aligned(16))) uint32_t qt_w[4][64][16];
  __shared__ __attribute__((aligned(16))) u16 w_lds[4][16][32];   // [wave][class][query]
  __shared__ float redden[16];

  const int tid = threadIdx.x;
  const int lane = tid & 63;
  const int wv = tid >> 6;
  const int c = lane & 15;   // class col (GEMM1 B / GEMM2 A m-index)
  const int g = lane >> 4;   // 0..3

  // centroid B-fragments as fp8 hi+lo split: c' = hi+lo carries ~8 mantissa bits.
  // csq computed from c' (self-consistent with the MFMA scores).
  const float* cent = ws + WS_CENT;
  const int cb = c * 64 + g * 8;
  uint32_t bh0a, bl0a, bh0b, bl0b, bh1a, bl1a, bh1b, bl1b;
  float csq = 0.f;
  quant_hilo4(cent[cb + 0], cent[cb + 1], cent[cb + 2], cent[cb + 3], bh0a, bl0a, csq);
  quant_hilo4(cent[cb + 4], cent[cb + 5], cent[cb + 6], cent[cb + 7], bh0b, bl0b, csq);
  quant_hilo4(cent[cb + 32], cent[cb + 33], cent[cb + 34], cent[cb + 35], bh1a, bl1a, csq);
  quant_hilo4(cent[cb + 36], cent[cb + 37], cent[cb + 38], cent[cb + 39], bh1b, bl1b, csq);
  csq += __shfl_xor(csq, 16);   // sum the 4 g-groups -> full 64-dim |c'|^2
  csq += __shfl_xor(csq, 32);
  const i64 bh0 = pack64(bh0a, bh0b), bl0 = pack64(bl0a, bl0b);
  const i64 bh1 = pack64(bh1a, bh1b), bl1 = pack64(bl1a, bl1b);

  f32x4 acc[4];
#pragma unroll
  for (int nt = 0; nt < 4; ++nt) acc[nt] = (f32x4){0.f, 0.f, 0.f, 0.f};
  float denacc = 0.f;

  const uint32_t psel = (c & 1) ? 0x03020706u : 0x05040100u;

  const int wave_id = blockIdx.x * 4 + wv;
  const int nwaves = gridDim.x * 4;
  const int ntiles = NQ >> 5;  // 32 queries per wave-tile

  for (int tile = wave_id; tile < ntiles; tile += nwaves) {
    const int qbase = tile << 5;
#pragma unroll
    for (int st = 0; st < 2; ++st) {
      const int q = qbase + st * 16 + c;  // A-frag: m = lane&15 = query
      u32x2 a0u, a1u;                     // 8+8 e4m3 bytes (dims g*8.., 32+g*8..)
      if (SRC_F8) {
        const uint8_t* qrow = q8 + (size_t)q * 64;
        a0u = *(const u32x2*)(qrow + g * 8);
        a1u = *(const u32x2*)(qrow + 32 + g * 8);
      } else {
        const float* qrow = qf + (size_t)q * 64 + g * 8;
        a0u[0] = pk8(qrow[0], qrow[1], qrow[2], qrow[3]);
        a0u[1] = pk8(qrow[4], qrow[5], qrow[6], qrow[7]);
        a1u[0] = pk8(qrow[32], qrow[33], qrow[34], qrow[35]);
        a1u[1] = pk8(qrow[36], qrow[37], qrow[38], qrow[39]);
      }
      const i64 a0 = __builtin_bit_cast(i64, a0u);
      const i64 a1 = __builtin_bit_cast(i64, a1u);
      f32x4 sc = (f32x4){0.f, 0.f, 0.f, 0.f};
      sc = __builtin_amdgcn_mfma_f32_16x16x32_fp8_fp8(a0, bh0, sc, 0, 0, 0);
      sc = __builtin_amdgcn_mfma_f32_16x16x32_fp8_fp8(a0, bl0, sc, 0, 0, 0);
      sc = __builtin_amdgcn_mfma_f32_16x16x32_fp8_fp8(a1, bh1, sc, 0, 0, 0);
      sc = __builtin_amdgcn_mfma_f32_16x16x32_fp8_fp8(a1, bl1, sc, 0, 0, 0);
      // D layout: lane holds queries (st*16 + g*4 + r), class c.
      // softmax over classes == across the 16-lane row (q_sq cancels) — DPP, VALU pipe
      float wr[4];
#pragma unroll
      for (int r = 0; r < 4; ++r) {
        float sv = BETA_F * (2.f * sc[r] - csq);
        float m = rmax16(sv);
        float e = __expf(sv - m);
        float s = rsum16(e);
        wr[r] = e * __builtin_amdgcn_rcpf(s);
      }
      uint32_t wlo = cvt_pk_bf16(wr[0], wr[1]);
      uint32_t whi = cvt_pk_bf16(wr[2], wr[3]);
      *(uint2*)&w_lds[wv][c][st * 16 + g * 4] = make_uint2(wlo, whi);
      // den self-consistent with bf16-quantized numerator weights
      denacc += u2f(wlo << 16) + u2f(wlo & 0xFFFF0000u) +
                u2f(whi << 16) + u2f(whi & 0xFFFF0000u);

      // exact fp8 -> bf16 reconstruction (e4m3 ⊂ bf16), then the DPP+perm transpose:
      // even lane writes dim g*8+2p, odd lane dim g*8+2p+1. 2-way banked (free).
      uint32_t ua[4], ub[4];
      {
        f32x2 t0 = __builtin_amdgcn_cvt_pk_f32_fp8((int)a0u[0], false);
        f32x2 t1 = __builtin_amdgcn_cvt_pk_f32_fp8((int)a0u[0], true);
        f32x2 t2 = __builtin_amdgcn_cvt_pk_f32_fp8((int)a0u[1], false);
        f32x2 t3 = __builtin_amdgcn_cvt_pk_f32_fp8((int)a0u[1], true);
        ua[0] = cvt_pk_bf16(t0[0], t0[1]);
        ua[1] = cvt_pk_bf16(t1[0], t1[1]);
        ua[2] = cvt_pk_bf16(t2[0], t2[1]);
        ua[3] = cvt_pk_bf16(t3[0], t3[1]);
        t0 = __builtin_amdgcn_cvt_pk_f32_fp8((int)a1u[0], false);
        t1 = __builtin_amdgcn_cvt_pk_f32_fp8((int)a1u[0], true);
        t2 = __builtin_amdgcn_cvt_pk_f32_fp8((int)a1u[1], false);
        t3 = __builtin_amdgcn_cvt_pk_f32_fp8((int)a1u[1], true);
        ub[0] = cvt_pk_bf16(t0[0], t0[1]);
        ub[1] = cvt_pk_bf16(t1[0], t1[1]);
        ub[2] = cvt_pk_bf16(t2[0], t2[1]);
        ub[3] = cvt_pk_bf16(t3[0], t3[1]);
      }
      const int drow = g * 8 + (c & 1);
      const int wcol = ((st << 3) + (c >> 1)) ^ (g << 2);
#pragma unroll
      for (int p = 0; p < 4; ++p) {
        uint32_t m0 = ua[p];
        uint32_t n0 = dppu<0xB1>(m0);
        qt_w[wv][drow + 2 * p][wcol] = __builtin_amdgcn_perm(n0, m0, psel);
        uint32_t m1 = ub[p];
        uint32_t n1 = dppu<0xB1>(m1);
        qt_w[wv][32 + drow + 2 * p][wcol] = __builtin_amdgcn_perm(n1, m1, psel);
      }
    }
    // GEMM2: OUT[16 class][64 dim] += W^T @ Q over K=32 queries (wave-private, no barrier)
    bf16x8 aw = *(const bf16x8*)&w_lds[wv][c][g * 8];
#pragma unroll
    for (int nt = 0; nt < 4; ++nt) {
      const int K = ((nt << 1) + (c >> 3)) & 3;
      bf16x8 bq = *(const bf16x8*)&qt_w[wv][nt * 16 + c][(g ^ K) << 2];
      acc[nt] = __builtin_amdgcn_mfma_f32_16x16x32_bf16(aw, bq, acc[nt], 0, 0, 0);
    }
  }

  // block reduction (reuse wave-0 qt region as 1024-float scratch), then replicated atomics
  __syncthreads();
  float* red = (float*)&qt_w[0][0][0];
  for (int i = tid; i < 1024; i += 256) red[i] = 0.f;
  if (tid < 16) redden[tid] = 0.f;
  __syncthreads();
#pragma unroll
  for (int nt = 0; nt < 4; ++nt)
#pragma unroll
    for (int r = 0; r < 4; ++r)
      atomicAdd(&red[(g * 4 + r) * 64 + nt * 16 + c], acc[nt][r]);
  atomicAdd(&redden[c], denacc);
  __syncthreads();
  float* accn = ws + WS_ACC + (size_t)(blockIdx.x & 7) * 1040;
  for (int i = tid; i < 1024; i += 256) atomicAdd(&accn[i], red[i]);
  if (tid < 16) atomicAdd(&accn[1024 + tid], redden[tid]);
}

// ---------- centroid update ----------
__global__ __launch_bounds__(1024) void update_kernel(float* __restrict__ ws) {
  const int tid = threadIdx.x;
  const int c = tid >> 6;
  float num = ws[WS_SUPSUM + tid];
  float den = ws[WS_COUNTS + c];
#pragma unroll
  for (int rep = 0; rep < 8; ++rep) {
    num += ws[WS_ACC + rep * 1040 + tid];
    den += ws[WS_ACC + rep * 1040 + 1024 + c];
  }
  ws[WS_CENT + tid] = num / den;
  for (int i = tid; i < 8 * 1040; i += 1024) ws[WS_ACC + i] = 0.f;
  __syncthreads();
  if ((tid & 63) == 0) {
    float sq = 0.f;
    for (int k = 0; k < 64; ++k) { float v = ws[WS_CENT + c * 64 + k]; sq += v * v; }
    ws[WS_CSQ + c] = sq;
  }
}

// ---------- final argmin + accuracy count (fp32 source: best precision, read once) ----------
__global__ __launch_bounds__(256, 4) void final_kernel(const float* __restrict__ qf,
                                                       const int* __restrict__ qlab,
                                                       int NQ, float* __restrict__ ws) {
  const int tid = threadIdx.x;
  const int lane = tid & 63;
  const int c = lane & 15;
  const int g = lane >> 4;

  const float* cent = ws + WS_CENT;
  bf16x8 bc0, bc1;
#pragma unroll
  for (int j = 0; j < 8; ++j) {
    bc0[j] = (short)f2bf(cent[c * 64 + g * 8 + j]);
    bc1[j] = (short)f2bf(cent[c * 64 + 32 + g * 8 + j]);
  }
  const float csq = ws[WS_CSQ + c];

  int cnt = 0;
  const int wave_id = blockIdx.x * 4 + (tid >> 6);
  const int nwaves = gridDim.x * 4;
  const int ntiles = NQ >> 4;  // 16 queries per tile

  for (int tile = wave_id; tile < ntiles; tile += nwaves) {
    const int qbase = tile << 4;
    const int q = qbase + c;
    const float* qrow = qf + (size_t)q * 64;
    bf16x8 a0, a1;
#pragma unroll
    for (int j = 0; j < 8; ++j) {
      a0[j] = (short)f2bf(qrow[g * 8 + j]);
      a1[j] = (short)f2bf(qrow[32 + g * 8 + j]);
    }
    f32x4 sc = (f32x4){0.f, 0.f, 0.f, 0.f};
    sc = __builtin_amdgcn_mfma_f32_16x16x32_bf16(a0, bc0, sc, 0, 0, 0);
    sc = __builtin_amdgcn_mfma_f32_16x16x32_bf16(a1, bc1, sc, 0, 0, 0);
#pragma unroll
    for (int r = 0; r < 4; ++r) {
      float val = 2.f * sc[r] - csq;  // argmax(val) == argmin(d2)
      uint32_t key = (fkey(val) & 0xFFFFFFF0u) | (uint32_t)(15 - c);
      key = rumax16(key);
      int pred = 15 - (int)(key & 15u);
      if (c == 0) cnt += (qlab[qbase + g * 4 + r] == pred) ? 1 : 0;
    }
  }
#pragma unroll
  for (int msk = 1; msk < 64; msk <<= 1) cnt += __shfl_xor(cnt, msk);
  if (lane == 0) atomicAdd(&ws[WS_CORR], (float)cnt);
}

__global__ void finalize_kernel(const float* __restrict__ ws, float* __restrict__ out, float inv) {
  out[0] = ws[WS_CORR] * inv;
}

extern "C" void kernel_launch(void* const* d_in, const int* in_sizes, int n_in,
                              void* d_out, int out_size, void* d_ws, size_t ws_size,
                              hipStream_t stream) {
  const float* sup = (const float*)d_in[0];
  const float* qf  = (const float*)d_in[1];
  const int* slab  = (const int*)d_in[2];
  const int* qlab  = (const int*)d_in[3];
  float* ws = (float*)d_ws;
  float* out = (float*)d_out;
  const int NS = in_sizes[0] / 64;
  const int NQ = in_sizes[1] / 64;
  uint8_t* q8 = (uint8_t*)(ws + WS_Q8_OFF);
  const size_t need = (size_t)WS_Q8_OFF * 4 + (size_t)NQ * 64;
  const bool use_f8 = (ws_size >= need);

  init_kernel<<<1, 1024, 0, stream>>>(sup, slab, NS, ws);
  if (use_f8) convert_kernel<<<4096, 256, 0, stream>>>(qf, (u32x4*)q8, NQ * 4);
  for (int it = 0; it < ITERS; ++it) {
    if (use_f8) pass_kernel<true><<<2048, 256, 0, stream>>>(qf, q8, NQ, ws);
    else        pass_kernel<false><<<2048, 256, 0, stream>>>(qf, q8, NQ, ws);
    update_kernel<<<1, 1024, 0, stream>>>(ws);
  }
  final_kernel<<<2048, 256, 0, stream>>>(qf, qlab, NQ, ws);
  finalize_kernel<<<1, 1, 0, stream>>>(ws, out, 1.0f / (float)NQ);
}

// Round 2
// 5243.999 us; speedup vs baseline: 1.1214x; 1.1214x over previous
//
#include <hip/hip_runtime.h>
#include <stdint.h>

typedef short bf16x8 __attribute__((ext_vector_type(8)));
typedef float f32x4 __attribute__((ext_vector_type(4)));
typedef float f32x2 __attribute__((ext_vector_type(2)));
typedef uint32_t u32x4 __attribute__((ext_vector_type(4)));
typedef uint32_t u32x2 __attribute__((ext_vector_type(2)));
typedef int i32x2 __attribute__((ext_vector_type(2)));
typedef unsigned short u16;
typedef long long i64;

#define ITERS 50
#define BETA_F 5.0f

// ws layout (float offsets)
#define WS_SUPSUM 0       // 1024: per-class support sums [16][64]
#define WS_COUNTS 1024    // 16
#define WS_CENT   1040    // 1024: centroids [16][64]
#define WS_CSQ    2064    // 16: |centroid|^2 (fp32, used by final)
#define WS_ACC    2080    // 8 replicas x (1024 num + 16 den)
#define WS_CORR   10400   // 1: correct-count
#define WS_Q8_OFF 10432   // fp8(e4m3) query cache (permuted rows), NQ*64 bytes

__device__ __forceinline__ u16 f2bf(float x) {
  union { float f; uint32_t u; } v; v.f = x;
  uint32_t r = (v.u + 0x7FFFu + ((v.u >> 16) & 1u)) >> 16;
  return (u16)r;
}
__device__ __forceinline__ uint32_t fkey(float f) {
  union { float f; uint32_t u; } v; v.f = f;
  return (v.u & 0x80000000u) ? ~v.u : (v.u | 0x80000000u);
}
// pack 4 floats -> 4 e4m3 bytes (RNE)
__device__ __forceinline__ uint32_t pk8(float a, float b, float c, float d) {
  int r = __builtin_amdgcn_cvt_pk_fp8_f32(a, b, 0, false);
  r = __builtin_amdgcn_cvt_pk_fp8_f32(c, d, r, true);
  return (uint32_t)r;
}
__device__ __forceinline__ i64 pack64(uint32_t lo, uint32_t hi) {
  return (i64)(((uint64_t)hi << 32) | (uint64_t)lo);
}
// quantize 4 floats -> fp8 hi + fp8 lo (residual); accumulate |hi+lo|^2 into sq
__device__ __forceinline__ void quant_hilo4(float v0, float v1, float v2, float v3,
                                            uint32_t& hi, uint32_t& lo, float& sq) {
  uint32_t h = pk8(v0, v1, v2, v3);
  float h0 = __builtin_amdgcn_cvt_f32_fp8((int)h, 0);
  float h1 = __builtin_amdgcn_cvt_f32_fp8((int)h, 1);
  float h2 = __builtin_amdgcn_cvt_f32_fp8((int)h, 2);
  float h3 = __builtin_amdgcn_cvt_f32_fp8((int)h, 3);
  uint32_t l = pk8(v0 - h0, v1 - h1, v2 - h2, v3 - h3);
  float c0 = h0 + __builtin_amdgcn_cvt_f32_fp8((int)l, 0);
  float c1 = h1 + __builtin_amdgcn_cvt_f32_fp8((int)l, 1);
  float c2 = h2 + __builtin_amdgcn_cvt_f32_fp8((int)l, 2);
  float c3 = h3 + __builtin_amdgcn_cvt_f32_fp8((int)l, 3);
  sq += c0 * c0 + c1 * c1 + c2 * c2 + c3 * c3;
  hi = h; lo = l;
}

// ---- hardware byte-transpose LDS read (gfx950): lane l, elem j reads
// lds[base + (l&15) + j*16 + (l>>4)*128] -> exactly the fp8 B-fragment of a
// packed [32 k][16 n] byte tile when all lanes pass base + (l&15) + (l>>4)*128.
__device__ __forceinline__ i32x2 ds_tr8(const uint8_t* p) {
#if defined(__has_builtin)
#if __has_builtin(__builtin_amdgcn_ds_read_tr8_b64)
#define HAVE_TR8 1
#endif
#endif
#ifdef HAVE_TR8
  typedef __attribute__((address_space(3))) i32x2 lds_i32x2;
  return __builtin_amdgcn_ds_read_tr8_b64((lds_i32x2*)p);
#else
  uint32_t off = (uint32_t)(uintptr_t)(__attribute__((address_space(3))) const void*)p;
  i32x2 r;
  asm volatile("ds_read_b64_tr_b8 %0, %1\n\ts_waitcnt lgkmcnt(0)"
               : "=v"(r) : "v"(off) : "memory");
  __builtin_amdgcn_sched_barrier(0);
  return r;
#endif
}

// ---- DPP cross-lane (VALU pipe, not LDS) ----
template <int CTRL>
__device__ __forceinline__ float dppf(float x) {
  int i = __builtin_bit_cast(int, x);
  int r = __builtin_amdgcn_update_dpp(i, i, CTRL, 0xF, 0xF, false);
  return __builtin_bit_cast(float, r);
}
template <int CTRL>
__device__ __forceinline__ uint32_t dppu(uint32_t x) {
  int r = __builtin_amdgcn_update_dpp((int)x, (int)x, CTRL, 0xF, 0xF, false);
  return (uint32_t)r;
}
__device__ __forceinline__ float rmax16(float x) {
  x = fmaxf(x, dppf<0xB1>(x));
  x = fmaxf(x, dppf<0x4E>(x));
  x = fmaxf(x, dppf<0x141>(x));
  x = fmaxf(x, dppf<0x140>(x));
  return x;
}
__device__ __forceinline__ float rsum16(float x) {
  x += dppf<0xB1>(x);
  x += dppf<0x4E>(x);
  x += dppf<0x141>(x);
  x += dppf<0x140>(x);
  return x;
}
__device__ __forceinline__ uint32_t rumax16(uint32_t x) {
  uint32_t t;
  t = dppu<0xB1>(x);  x = (t > x) ? t : x;
  t = dppu<0x4E>(x);  x = (t > x) ? t : x;
  t = dppu<0x141>(x); x = (t > x) ? t : x;
  t = dppu<0x140>(x); x = (t > x) ? t : x;
  return x;
}

// ---------- init: support sums, counts, initial centroids, zero accumulators ----------
__global__ __launch_bounds__(1024) void init_kernel(const float* __restrict__ sup,
                                                    const int* __restrict__ slab,
                                                    int NS, float* __restrict__ ws) {
  const int tid = threadIdx.x;
  const int c = tid >> 6, j = tid & 63;
  float s = 0.f; int cnt = 0;
  for (int i = 0; i < NS; ++i) {
    int lbl = slab[i];
    float v = sup[i * 64 + j];
    if (lbl == c) { s += v; cnt++; }
  }
  ws[WS_SUPSUM + tid] = s;
  if (j == 0) ws[WS_COUNTS + c] = (float)cnt;
  ws[WS_CENT + tid] = s / (float)cnt;
  for (int i = tid; i < 8 * 1040; i += 1024) ws[WS_ACC + i] = 0.f;
  if (tid == 0) ws[WS_CORR] = 0.f;
  __syncthreads();
  if (j == 0) {
    float sq = 0.f;
    for (int k = 0; k < 64; ++k) { float v = ws[WS_CENT + c * 64 + k]; sq += v * v; }
    ws[WS_CSQ + c] = sq;
  }
}

// ---------- one soft-assignment pass: fp8 scores -> softmax -> W^T@Q (all-fp8 GEMM2) ----------
// Cache row layout (written by the WRC8 pass): byte chunk g*16.. holds dims
// {g*8..g*8+7, 32+g*8..32+g*8+7} -> each lane loads its 16 B with ONE dwordx4.
template <bool SRC_F8, bool WRC8>
__global__ __launch_bounds__(256, 4) void pass_kernel(const float* __restrict__ qf,
                                                      uint8_t* __restrict__ q8,
                                                      int NQ, float* __restrict__ ws) {
  // qt8[wave]: packed B-tiles [4 nt][32 q][16 d] bytes (512 B per nt-subtile)
  __shared__ __attribute__((aligned(16))) uint8_t qt8[4][2048];
  __shared__ __attribute__((aligned(16))) uint8_t w8[4][16][32];  // [wave][class][query] e4m3
  __shared__ float redden[16];

  const int tid = threadIdx.x;
  const int lane = tid & 63;
  const int wv = tid >> 6;
  const int c = lane & 15;   // class col (GEMM1 B-n / GEMM2 A-m); also query row in A-frag
  const int g = lane >> 4;   // 0..3

  // centroid B-fragments as fp8 hi+lo split (~8 mantissa bits); csq from quantized c'
  const float* cent = ws + WS_CENT;
  const int cb = c * 64 + g * 8;
  uint32_t bh0a, bl0a, bh0b, bl0b, bh1a, bl1a, bh1b, bl1b;
  float csq = 0.f;
  quant_hilo4(cent[cb + 0], cent[cb + 1], cent[cb + 2], cent[cb + 3], bh0a, bl0a, csq);
  quant_hilo4(cent[cb + 4], cent[cb + 5], cent[cb + 6], cent[cb + 7], bh0b, bl0b, csq);
  quant_hilo4(cent[cb + 32], cent[cb + 33], cent[cb + 34], cent[cb + 35], bh1a, bl1a, csq);
  quant_hilo4(cent[cb + 36], cent[cb + 37], cent[cb + 38], cent[cb + 39], bh1b, bl1b, csq);
  csq += __shfl_xor(csq, 16);
  csq += __shfl_xor(csq, 32);
  const i64 bh0 = pack64(bh0a, bh0b), bl0 = pack64(bl0a, bl0b);
  const i64 bh1 = pack64(bh1a, bh1b), bl1 = pack64(bl1a, bl1b);
  const float kcn = -BETA_F * csq;   // logit = fma(sc, 2*beta, kcn)

  f32x4 acc[4] = {};
  float denacc = 0.f;

  uint8_t* qtw = &qt8[wv][0];
  const uint8_t* trb = qtw + c + g * 128;              // tr8 per-lane base
  uint8_t* w8w = &w8[wv][c][0];
  const int woff = (g >> 1) * 512 + (g & 1) * 8;       // + row*16 (+1024 for high dims)

  const int wave_id = blockIdx.x * 4 + wv;
  const int nwaves = gridDim.x * 4;
  const int ntiles = NQ >> 5;  // 32 queries per wave-tile

  auto LOADQ = [&](int tl, u32x2 (&da)[2], u32x2 (&db)[2]) {
    const int qb0 = tl << 5;
#pragma unroll
    for (int st = 0; st < 2; ++st) {
      const int q = qb0 + st * 16 + c;
      if (SRC_F8) {
        u32x4 v = *(const u32x4*)(q8 + (size_t)q * 64 + g * 16);
        da[st][0] = v[0]; da[st][1] = v[1];
        db[st][0] = v[2]; db[st][1] = v[3];
      } else {
        const float* qr = qf + (size_t)q * 64 + g * 8;
        f32x4 v0 = *(const f32x4*)(qr);
        f32x4 v1 = *(const f32x4*)(qr + 4);
        f32x4 v2 = *(const f32x4*)(qr + 32);
        f32x4 v3 = *(const f32x4*)(qr + 36);
        da[st][0] = pk8(v0[0], v0[1], v0[2], v0[3]);
        da[st][1] = pk8(v1[0], v1[1], v1[2], v1[3]);
        db[st][0] = pk8(v2[0], v2[1], v2[2], v2[3]);
        db[st][1] = pk8(v3[0], v3[1], v3[2], v3[3]);
        if (WRC8) {
          u32x4 o; o[0] = da[st][0]; o[1] = da[st][1]; o[2] = db[st][0]; o[3] = db[st][1];
          *(u32x4*)(q8 + (size_t)q * 64 + g * 16) = o;
        }
      }
    }
  };

  u32x2 qa[2] = {}, qb_[2] = {}, na_[2] = {}, nb_[2] = {};
  int tile = wave_id;
  if (tile < ntiles) LOADQ(tile, qa, qb_);
  for (; tile < ntiles; tile += nwaves) {
    if (tile + nwaves < ntiles) LOADQ(tile + nwaves, na_, nb_);  // prefetch
#pragma unroll
    for (int st = 0; st < 2; ++st) {
      const int row = st * 16 + c;
      // stage raw fp8 Q into packed B-tiles (plain b64 writes, natural order)
      *(u32x2*)(qtw + woff + row * 16) = qa[st];           // dims g*8..  -> nt = g>>1
      *(u32x2*)(qtw + woff + row * 16 + 1024) = qb_[st];   // dims 32+g*8 -> nt = 2+(g>>1)
      const i64 a0 = __builtin_bit_cast(i64, qa[st]);
      const i64 a1 = __builtin_bit_cast(i64, qb_[st]);
      f32x4 sc4 = {};
      sc4 = __builtin_amdgcn_mfma_f32_16x16x32_fp8_fp8(a0, bh0, sc4, 0, 0, 0);
      sc4 = __builtin_amdgcn_mfma_f32_16x16x32_fp8_fp8(a0, bl0, sc4, 0, 0, 0);
      sc4 = __builtin_amdgcn_mfma_f32_16x16x32_fp8_fp8(a1, bh1, sc4, 0, 0, 0);
      sc4 = __builtin_amdgcn_mfma_f32_16x16x32_fp8_fp8(a1, bl1, sc4, 0, 0, 0);
      // D: lane holds queries (st*16 + g*4 + r), class c. Softmax across 16-lane row.
      float wr[4];
#pragma unroll
      for (int r = 0; r < 4; ++r) {
        float sv = fmaf(sc4[r], 2.0f * BETA_F, kcn);
        float m = rmax16(sv);
        float e = __expf(sv - m);
        float s = rsum16(e);
        wr[r] = e * __builtin_amdgcn_rcpf(s);
      }
      uint32_t w32 = pk8(wr[0], wr[1], wr[2], wr[3]);     // weights as e4m3
      *(uint32_t*)(w8w + st * 16 + g * 4) = w32;
      // den self-consistent with quantized numerator weights
      f32x2 d0 = __builtin_amdgcn_cvt_pk_f32_fp8((int)w32, false);
      f32x2 d1 = __builtin_amdgcn_cvt_pk_f32_fp8((int)w32, true);
      denacc += (d0[0] + d0[1]) + (d1[0] + d1[1]);
    }
    // GEMM2 (all fp8): OUT[16 class][64 dim] += W^T @ Q over K=32 (wave-private)
    const i64 aw = *(const i64*)(w8w + g * 8);  // A: m=class c, k=queries g*8..+7
#pragma unroll
    for (int nt = 0; nt < 4; ++nt) {
      i32x2 bq = ds_tr8(trb + nt * 512);        // B: n=dim (nt*16+c'), k=queries
      acc[nt] = __builtin_amdgcn_mfma_f32_16x16x32_fp8_fp8(
          aw, __builtin_bit_cast(i64, bq), acc[nt], 0, 0, 0);
    }
#pragma unroll
    for (int st = 0; st < 2; ++st) { qa[st] = na_[st]; qb_[st] = nb_[st]; }
  }

  // block reduction (reuse qt8 as 1024-float scratch), then replicated atomics
  __syncthreads();
  float* red = (float*)&qt8[0][0];
  for (int i = tid; i < 1024; i += 256) red[i] = 0.f;
  if (tid < 16) redden[tid] = 0.f;
  __syncthreads();
#pragma unroll
  for (int nt = 0; nt < 4; ++nt)
#pragma unroll
    for (int r = 0; r < 4; ++r)
      atomicAdd(&red[(g * 4 + r) * 64 + nt * 16 + c], acc[nt][r]);
  atomicAdd(&redden[c], denacc);
  __syncthreads();
  float* accn = ws + WS_ACC + (size_t)(blockIdx.x & 7) * 1040;
  for (int i = tid; i < 1024; i += 256) atomicAdd(&accn[i], red[i]);
  if (tid < 16) atomicAdd(&accn[1024 + tid], redden[tid]);
}

// ---------- centroid update ----------
__global__ __launch_bounds__(1024) void update_kernel(float* __restrict__ ws) {
  const int tid = threadIdx.x;
  const int c = tid >> 6;
  float num = ws[WS_SUPSUM + tid];
  float den = ws[WS_COUNTS + c];
#pragma unroll
  for (int rep = 0; rep < 8; ++rep) {
    num += ws[WS_ACC + rep * 1040 + tid];
    den += ws[WS_ACC + rep * 1040 + 1024 + c];
  }
  ws[WS_CENT + tid] = num / den;
  for (int i = tid; i < 8 * 1040; i += 1024) ws[WS_ACC + i] = 0.f;
  __syncthreads();
  if ((tid & 63) == 0) {
    float sq = 0.f;
    for (int k = 0; k < 64; ++k) { float v = ws[WS_CENT + c * 64 + k]; sq += v * v; }
    ws[WS_CSQ + c] = sq;
  }
}

// ---------- final argmin + accuracy count (fp32 source: best precision, read once) ----------
__global__ __launch_bounds__(256, 4) void final_kernel(const float* __restrict__ qf,
                                                       const int* __restrict__ qlab,
                                                       int NQ, float* __restrict__ ws) {
  const int tid = threadIdx.x;
  const int lane = tid & 63;
  const int c = lane & 15;
  const int g = lane >> 4;

  const float* cent = ws + WS_CENT;
  bf16x8 bc0, bc1;
#pragma unroll
  for (int j = 0; j < 8; ++j) {
    bc0[j] = (short)f2bf(cent[c * 64 + g * 8 + j]);
    bc1[j] = (short)f2bf(cent[c * 64 + 32 + g * 8 + j]);
  }
  const float csq = ws[WS_CSQ + c];

  int cnt = 0;
  const int wave_id = blockIdx.x * 4 + (tid >> 6);
  const int nwaves = gridDim.x * 4;
  const int ntiles = NQ >> 4;  // 16 queries per tile

  for (int tile = wave_id; tile < ntiles; tile += nwaves) {
    const int qbase = tile << 4;
    const int q = qbase + c;
    const float* qrow = qf + (size_t)q * 64;
    bf16x8 a0, a1;
#pragma unroll
    for (int j = 0; j < 8; ++j) {
      a0[j] = (short)f2bf(qrow[g * 8 + j]);
      a1[j] = (short)f2bf(qrow[32 + g * 8 + j]);
    }
    f32x4 sc = (f32x4){0.f, 0.f, 0.f, 0.f};
    sc = __builtin_amdgcn_mfma_f32_16x16x32_bf16(a0, bc0, sc, 0, 0, 0);
    sc = __builtin_amdgcn_mfma_f32_16x16x32_bf16(a1, bc1, sc, 0, 0, 0);
#pragma unroll
    for (int r = 0; r < 4; ++r) {
      float val = 2.f * sc[r] - csq;  // argmax(val) == argmin(d2)
      uint32_t key = (fkey(val) & 0xFFFFFFF0u) | (uint32_t)(15 - c);
      key = rumax16(key);
      int pred = 15 - (int)(key & 15u);
      if (c == 0) cnt += (qlab[qbase + g * 4 + r] == pred) ? 1 : 0;
    }
  }
#pragma unroll
  for (int msk = 1; msk < 64; msk <<= 1) cnt += __shfl_xor(cnt, msk);
  if (lane == 0) atomicAdd(&ws[WS_CORR], (float)cnt);
}

__global__ void finalize_kernel(const float* __restrict__ ws, float* __restrict__ out, float inv) {
  out[0] = ws[WS_CORR] * inv;
}

extern "C" void kernel_launch(void* const* d_in, const int* in_sizes, int n_in,
                              void* d_out, int out_size, void* d_ws, size_t ws_size,
                              hipStream_t stream) {
  const float* sup = (const float*)d_in[0];
  const float* qf  = (const float*)d_in[1];
  const int* slab  = (const int*)d_in[2];
  const int* qlab  = (const int*)d_in[3];
  float* ws = (float*)d_ws;
  float* out = (float*)d_out;
  const int NS = in_sizes[0] / 64;
  const int NQ = in_sizes[1] / 64;
  uint8_t* q8 = (uint8_t*)(ws + WS_Q8_OFF);
  const size_t need = (size_t)WS_Q8_OFF * 4 + (size_t)NQ * 64;
  const bool use_f8 = (ws_size >= need);

  init_kernel<<<1, 1024, 0, stream>>>(sup, slab, NS, ws);
  for (int it = 0; it < ITERS; ++it) {
    if (it == 0) {
      if (use_f8) pass_kernel<false, true><<<2048, 256, 0, stream>>>(qf, q8, NQ, ws);
      else        pass_kernel<false, false><<<2048, 256, 0, stream>>>(qf, q8, NQ, ws);
    } else {
      if (use_f8) pass_kernel<true, false><<<2048, 256, 0, stream>>>(qf, q8, NQ, ws);
      else        pass_kernel<false, false><<<2048, 256, 0, stream>>>(qf, q8, NQ, ws);
    }
    update_kernel<<<1, 1024, 0, stream>>>(ws);
  }
  final_kernel<<<2048, 256, 0, stream>>>(qf, qlab, NQ, ws);
  finalize_kernel<<<1, 1, 0, stream>>>(ws, out, 1.0f / (float)NQ);
}